// Round 14
// baseline (96.977 us; speedup 1.0000x reference)
//
#include <hip/hip_runtime.h>
#include <math.h>

// LossLayer: dist[b,r] = ||W[b]-R[r]||2 ; pred = one_hot(argmax_r dist) ;
// loss = mean(1 + dist[b,y] - dist[b, top2-excluding-y-at-top1]), y=argmax(label[b])
//
// R14 (on R13): the dominant cycle term is per-wave full-re LDS sweeps
// (each wave reads all 128 KB). Halve wave count: JB=4 rows/wave, WVS=4,
// block 256, grid 256 (1 block/CU, 1 wave/SIMD). Per-CU LDS traffic halves
// (512 KB ~ 6.1K cyc), waves 2048->1024, epilogues halve; VALU/SIMD ~equal.
// W batch/group = 32 named f4 (~190 VGPR live; no launch_bounds cap, <=512
// physical -> no spill; R2/R4 spills were cap-induced). Rest = proven R13:
// merged transpose staging into stride-65-padded LDS (writes <=8-way one-time,
// hot reads lane-consecutive conflict-free), uniform-address W vmcnt stream,
// packed f4v math, ONE barrier, fused loss reduction.
#define NB 4096
#define NR 64
#define JB 4            // b-rows per wave
#define WVS 4           // waves per block (256 threads)
#define BBB (JB * WVS)  // 16 b-rows per block; grid = 256

typedef float f4v __attribute__((ext_vector_type(4)));

__global__ __launch_bounds__(256) void fused_loss_kernel(
    const float* __restrict__ w,
    const float* __restrict__ re,
    const float* __restrict__ label,
    float* __restrict__ out,
    float* __restrict__ ws)
{
    __shared__ f4v rl[128 * 65];    // transposed+padded re: slot=d4*65+r, 130 KB
    __shared__ float terms[WVS];

    const int tid = threadIdx.x;
    const int wv  = tid >> 6;       // wave id 0..3
    const int r   = tid & 63;       // lane = relation 0..63
    const int b0  = blockIdx.x * BBB;

    // ---- stage re row-major -> LDS transposed (one-time) ----
    const f4v* re4g = (const f4v*)re;
    #pragma unroll
    for (int i = 0; i < 32; i++) {
        int idx = i * 256 + tid;                 // row=idx>>7, d4=idx&127
        f4v v = re4g[idx];                       // coalesced; consumed at once
        rl[(idx & 127) * 65 + (idx >> 7)] = v;
    }

    // ---- hoisted label loads ----
    const int b_0 = b0 + wv * JB;
    float lv_0 = label[(size_t)(b_0 + 0) * 64 + r];
    float lv_1 = label[(size_t)(b_0 + 1) * 64 + r];
    float lv_2 = label[(size_t)(b_0 + 2) * 64 + r];
    float lv_3 = label[(size_t)(b_0 + 3) * 64 + r];

    // uniform W row pointers (readfirstlane -> scalar addr; broadcast data)
    const f4v *wr0, *wr1, *wr2, *wr3;
    {
        int u0 = __builtin_amdgcn_readfirstlane(b_0 + 0);
        int u1 = __builtin_amdgcn_readfirstlane(b_0 + 1);
        int u2 = __builtin_amdgcn_readfirstlane(b_0 + 2);
        int u3 = __builtin_amdgcn_readfirstlane(b_0 + 3);
        wr0 = (const f4v*)(w + (size_t)u0 * 512);
        wr1 = (const f4v*)(w + (size_t)u1 * 512);
        wr2 = (const f4v*)(w + (size_t)u2 * 512);
        wr3 = (const f4v*)(w + (size_t)u3 * 512);
    }

    f4v acc0 = {0.f,0.f,0.f,0.f}, acc1 = {0.f,0.f,0.f,0.f};
    f4v acc2 = {0.f,0.f,0.f,0.f}, acc3 = {0.f,0.f,0.f,0.f};

    __syncthreads();   // ONE drain: re resident+transposed; loop barrier-free

    // hot loop: 16 groups of 8 d4. Per group: 32 uniform W vector loads
    // (vmcnt broadcast, batch-issued) + 8 lane-consecutive ds_read_b128
    // (conflict-free) + packed-f4 FMA on 4 independent row chains.
    #pragma unroll 2
    for (int g = 0; g < 16; g++) {
        const int gb = g * 8;

        f4v qa0 = wr0[gb+0], qa1 = wr0[gb+1], qa2 = wr0[gb+2], qa3 = wr0[gb+3];
        f4v qa4 = wr0[gb+4], qa5 = wr0[gb+5], qa6 = wr0[gb+6], qa7 = wr0[gb+7];
        f4v qb0 = wr1[gb+0], qb1 = wr1[gb+1], qb2 = wr1[gb+2], qb3 = wr1[gb+3];
        f4v qb4 = wr1[gb+4], qb5 = wr1[gb+5], qb6 = wr1[gb+6], qb7 = wr1[gb+7];
        f4v qc0 = wr2[gb+0], qc1 = wr2[gb+1], qc2 = wr2[gb+2], qc3 = wr2[gb+3];
        f4v qc4 = wr2[gb+4], qc5 = wr2[gb+5], qc6 = wr2[gb+6], qc7 = wr2[gb+7];
        f4v qd0 = wr3[gb+0], qd1 = wr3[gb+1], qd2 = wr3[gb+2], qd3 = wr3[gb+3];
        f4v qd4 = wr3[gb+4], qd5 = wr3[gb+5], qd6 = wr3[gb+6], qd7 = wr3[gb+7];

        const f4v* rp = &rl[gb * 65 + r];
        f4v v0 = rp[0*65], v1 = rp[1*65], v2 = rp[2*65], v3 = rp[3*65];
        f4v v4 = rp[4*65], v5 = rp[5*65], v6 = rp[6*65], v7 = rp[7*65];

#define STEP(qa, qb, qc, qd, vv)                                             \
        {                                                                    \
            f4v dxa = qa - vv;  acc0 = dxa * dxa + acc0;                     \
            f4v dxb = qb - vv;  acc1 = dxb * dxb + acc1;                     \
            f4v dxc = qc - vv;  acc2 = dxc * dxc + acc2;                     \
            f4v dxd = qd - vv;  acc3 = dxd * dxd + acc3;                     \
        }
        STEP(qa0,qb0,qc0,qd0,v0) STEP(qa1,qb1,qc1,qd1,v1)
        STEP(qa2,qb2,qc2,qd2,v2) STEP(qa3,qb3,qc3,qd3,v3)
        STEP(qa4,qb4,qc4,qd4,v4) STEP(qa5,qb5,qc5,qd5,v5)
        STEP(qa6,qb6,qc6,qd6,v6) STEP(qa7,qb7,qc7,qd7,v7)
#undef STEP
    }

    // ---- epilogue per j: top-2/argmax + label argmax + loss term ----
    float lsum = 0.0f;
    #pragma unroll
    for (int j = 0; j < JB; j++) {
        int b = b_0 + j;
        f4v accj = (j == 0) ? acc0 : ((j == 1) ? acc1 : ((j == 2) ? acc2 : acc3));
        float d = sqrtf((accj.x + accj.y) + (accj.z + accj.w));

        float m1 = d; int i1 = r; float m2 = -3.0e38f;
        #pragma unroll
        for (int mask = 1; mask <= 32; mask <<= 1) {
            float om1 = __shfl_xor(m1, mask, 64);
            int   oi1 = __shfl_xor(i1, mask, 64);
            float om2 = __shfl_xor(m2, mask, 64);
            bool ob1 = (om1 > m1) || (om1 == m1 && oi1 < i1);
            float w1 = ob1 ? om1 : m1;  int wi1 = ob1 ? oi1 : i1;
            float l1_ = ob1 ? m1 : om1;         // loser's top-1 (value only)
            float c2 = ob1 ? om2 : m2;          // winner's top-2 (value only)
            m1 = w1; i1 = wi1;
            m2 = (c2 > l1_) ? c2 : l1_;
        }

        float lv = (j == 0) ? lv_0 : ((j == 1) ? lv_1 : ((j == 2) ? lv_2 : lv_3));
        int ly = r;
        #pragma unroll
        for (int mask = 1; mask <= 32; mask <<= 1) {
            float ov = __shfl_xor(lv, mask, 64);
            int   oy = __shfl_xor(ly, mask, 64);
            if (ov > lv || (ov == lv && oy < ly)) { lv = ov; ly = oy; }
        }
        int y = ly;

        float plus  = __shfl(d, y, 64);       // dist[b][y]
        float minus = (i1 == y) ? m2 : m1;    // top-2 value if top-1 == y
        lsum += 1.0f + plus - minus;

        out[(size_t)b * 64 + r] = (i1 == r) ? 1.0f : 0.0f;   // pred one-hot
    }

    if (r == 0) terms[wv] = lsum;

    // ---- fused loss reduction: block partial -> device atomic -> last block
    __syncthreads();
    if (tid == 0) {
        float t = ((terms[0] + terms[1]) + (terms[2] + terms[3])) * (1.0f / NB);
        atomicAdd(ws, t);                     // ws[0] = loss accumulator (zeroed)
        __threadfence();                      // order add before counter inc
        unsigned old = atomicAdd((unsigned*)(ws + 1), 1u);   // ws[1] = counter
        if (old == (unsigned)(gridDim.x - 1)) {
            float total = atomicAdd(ws, 0.0f);   // all 256 adds visible
            out[(size_t)NB * NR] = total;
        }
    }
}

extern "C" void kernel_launch(void* const* d_in, const int* in_sizes, int n_in,
                              void* d_out, int out_size, void* d_ws, size_t ws_size,
                              hipStream_t stream) {
    const float* w   = (const float*)d_in[0];   // [4096,512]
    const float* re  = (const float*)d_in[1];   // [64,512]
    const float* lab = (const float*)d_in[2];   // [4096,64]
    float* out = (float*)d_out;                 // pred [4096,64] ++ loss [1]
    float* ws  = (float*)d_ws;                  // [0]=loss acc, [1]=done counter

    hipMemsetAsync(ws, 0, 8, stream);           // zero acc + counter (graph-safe)
    fused_loss_kernel<<<NB / BBB, 256, 0, stream>>>(w, re, lab, out, ws);
}

// Round 15
// 87.445 us; speedup vs baseline: 1.1090x; 1.1090x over previous
//
#include <hip/hip_runtime.h>
#include <math.h>

// LossLayer: dist[b,r] = ||W[b]-R[r]||2 ; pred = one_hot(argmax_r dist) ;
// loss = mean(1 + dist[b,y] - dist[b, top2-excluding-y-at-top1]), y=argmax(label[b])
//
// R15 (single-variable change on R13, the best total): eliminate the W memory
// stream from the hot loop entirely. A wave's 2 W rows = 256 f4 = 4 coalesced
// b128 loads -> 16 VGPRs/lane (lane l holds f4 l and 64+l of each row).
// Hot-loop W access = v_readlane (VALU ~2cyc, uniform SGPR index) -- SGPR
// result broadcasts straight into the FMA. R14's calibration: VALU issue is
// only ~8us; R13's ~30us was W-load latency (256 uniform loads x 300-900cyc,
// 2 waves to cover). Trade: +1024 readlane/wave (+2Kcyc VALU) for zero W
// latency. Hot loop's only memory = re ds_read_b128 batches (in-order lgkm,
// fine waits). All else R13-verbatim: merged transpose staging, stride-65
// padded LDS (130KB), block 512 / JB=2 / grid 256, epilogue, atomic tail.
#define NB 4096
#define NR 64
#define JB 2            // b-rows per wave
#define WVS 8           // waves per block (512 threads)
#define BBB (JB * WVS)  // 16 b-rows per block; grid = 256

typedef float f4v __attribute__((ext_vector_type(4)));

__device__ __forceinline__ float rdl(float x, int l) {
    return __int_as_float(__builtin_amdgcn_readlane(__float_as_int(x), l));
}

__global__ __launch_bounds__(512) void fused_loss_kernel(
    const float* __restrict__ w,
    const float* __restrict__ re,
    const float* __restrict__ label,
    float* __restrict__ out,
    float* __restrict__ ws)
{
    __shared__ f4v rl[128 * 65];    // transposed+padded re: slot=d4*65+r, 130 KB
    __shared__ float terms[WVS];

    const int tid = threadIdx.x;
    const int wv  = tid >> 6;       // wave id 0..7
    const int r   = tid & 63;       // lane = relation 0..63
    const int b0  = blockIdx.x * BBB;
    const int b_0 = b0 + wv * JB;
    const int b_1 = b_0 + 1;

    // ---- W rows into REGISTERS: 4 coalesced b128 loads, 16 VGPRs/lane ----
    // lane l holds row-d4 l (k=0) and 64+l (k=1) of each of the 2 rows.
    const f4v* wr0 = (const f4v*)(w + (size_t)b_0 * 512);
    const f4v* wr1 = (const f4v*)(w + (size_t)b_1 * 512);
    f4v wa0 = wr0[r], wa1 = wr0[64 + r];
    f4v wb0 = wr1[r], wb1 = wr1[64 + r];

    // ---- hoisted label loads ----
    float lv_0 = label[(size_t)b_0 * 64 + r];
    float lv_1 = label[(size_t)b_1 * 64 + r];

    // ---- stage re row-major -> LDS transposed (one-time, R13-verbatim) ----
    const f4v* re4g = (const f4v*)re;
    #pragma unroll
    for (int i = 0; i < 16; i++) {
        int idx = i * 512 + tid;                 // row=idx>>7, d4=idx&127
        f4v v = re4g[idx];                       // coalesced; consumed at once
        rl[(idx & 127) * 65 + (idx >> 7)] = v;
    }

    f4v acc0 = {0.f, 0.f, 0.f, 0.f};
    f4v acc1 = {0.f, 0.f, 0.f, 0.f};

    __syncthreads();   // ONE drain: re resident+transposed; loop barrier-free

    // hot loop: two halves (k=0: d4 0..63 from wa0/wb0; k=1: 64..127 from
    // wa1/wb1), 8 groups each. Per group: 8 lane-consecutive ds_read_b128
    // (conflict-free, batch-issued) + readlane W broadcasts + FMA.
    #pragma unroll 1
    for (int half = 0; half < 2; half++) {
        f4v qa = half ? wa1 : wa0;              // uniform select, once per half
        f4v qb = half ? wb1 : wb0;
        #pragma unroll 1
        for (int g = 0; g < 8; g++) {
            const int gb = half * 64 + g * 8;
            const f4v* rp = &rl[gb * 65 + r];
            f4v v0 = rp[0*65], v1 = rp[1*65], v2 = rp[2*65], v3 = rp[3*65];
            f4v v4 = rp[4*65], v5 = rp[5*65], v6 = rp[6*65], v7 = rp[7*65];

#define STEP(k, vv)                                                          \
            {                                                                \
                int l = g * 8 + (k);            /* uniform lane index */     \
                f4v q0 = { rdl(qa.x, l), rdl(qa.y, l),                       \
                           rdl(qa.z, l), rdl(qa.w, l) };                     \
                f4v q1 = { rdl(qb.x, l), rdl(qb.y, l),                       \
                           rdl(qb.z, l), rdl(qb.w, l) };                     \
                f4v dxa = q0 - vv;  acc0 = dxa * dxa + acc0;                 \
                f4v dxb = q1 - vv;  acc1 = dxb * dxb + acc1;                 \
            }
            STEP(0, v0) STEP(1, v1) STEP(2, v2) STEP(3, v3)
            STEP(4, v4) STEP(5, v5) STEP(6, v6) STEP(7, v7)
#undef STEP
        }
    }

    // ---- epilogue per j: top-2/argmax + label argmax + loss term ----
    float lsum = 0.0f;
    #pragma unroll
    for (int j = 0; j < JB; j++) {
        int b = (j == 0) ? b_0 : b_1;
        f4v accj = (j == 0) ? acc0 : acc1;
        float d = sqrtf((accj.x + accj.y) + (accj.z + accj.w));

        float m1 = d; int i1 = r; float m2 = -3.0e38f;
        #pragma unroll
        for (int mask = 1; mask <= 32; mask <<= 1) {
            float om1 = __shfl_xor(m1, mask, 64);
            int   oi1 = __shfl_xor(i1, mask, 64);
            float om2 = __shfl_xor(m2, mask, 64);
            bool ob1 = (om1 > m1) || (om1 == m1 && oi1 < i1);
            float w1 = ob1 ? om1 : m1;  int wi1 = ob1 ? oi1 : i1;
            float l1_ = ob1 ? m1 : om1;         // loser's top-1 (value only)
            float c2 = ob1 ? om2 : m2;          // winner's top-2 (value only)
            m1 = w1; i1 = wi1;
            m2 = (c2 > l1_) ? c2 : l1_;
        }

        float lv = (j == 0) ? lv_0 : lv_1; int ly = r;
        #pragma unroll
        for (int mask = 1; mask <= 32; mask <<= 1) {
            float ov = __shfl_xor(lv, mask, 64);
            int   oy = __shfl_xor(ly, mask, 64);
            if (ov > lv || (ov == lv && oy < ly)) { lv = ov; ly = oy; }
        }
        int y = ly;

        float plus  = __shfl(d, y, 64);       // dist[b][y]
        float minus = (i1 == y) ? m2 : m1;    // top-2 value if top-1 == y
        lsum += 1.0f + plus - minus;

        out[(size_t)b * 64 + r] = (i1 == r) ? 1.0f : 0.0f;   // pred one-hot
    }

    if (r == 0) terms[wv] = lsum;

    // ---- fused loss reduction: block partial -> device atomic -> last block
    __syncthreads();
    if (tid == 0) {
        float t = (((terms[0] + terms[1]) + (terms[2] + terms[3]))
                 + ((terms[4] + terms[5]) + (terms[6] + terms[7]))) * (1.0f / NB);
        atomicAdd(ws, t);                     // ws[0] = loss accumulator (zeroed)
        __threadfence();                      // order add before counter inc
        unsigned old = atomicAdd((unsigned*)(ws + 1), 1u);   // ws[1] = counter
        if (old == (unsigned)(gridDim.x - 1)) {
            float total = atomicAdd(ws, 0.0f);   // all 256 adds visible
            out[(size_t)NB * NR] = total;
        }
    }
}

extern "C" void kernel_launch(void* const* d_in, const int* in_sizes, int n_in,
                              void* d_out, int out_size, void* d_ws, size_t ws_size,
                              hipStream_t stream) {
    const float* w   = (const float*)d_in[0];   // [4096,512]
    const float* re  = (const float*)d_in[1];   // [64,512]
    const float* lab = (const float*)d_in[2];   // [4096,64]
    float* out = (float*)d_out;                 // pred [4096,64] ++ loss [1]
    float* ws  = (float*)d_ws;                  // [0]=loss acc, [1]=done counter

    hipMemsetAsync(ws, 0, 8, stream);           // zero acc + counter (graph-safe)
    fused_loss_kernel<<<NB / BBB, 512, 0, stream>>>(w, re, lab, out, ws);
}